// Round 1
// baseline (190.184 us; speedup 1.0000x reference)
//
#include <hip/hip_runtime.h>
#include <hip/hip_bf16.h>
#include <math.h>

#define D_K  512
#define NROW 8192
#define BM   128
#define BN   128
#define BK   64

typedef __attribute__((ext_vector_type(8))) short bf16x8;
typedef __attribute__((ext_vector_type(4))) float f32x4;

// f32 -> bf16 round-to-nearest-even (inputs are finite gaussians; no NaN path needed)
__device__ __forceinline__ unsigned short f2bf(float f) {
    unsigned int u = __float_as_uint(f);
    unsigned int r = (u + 0x7FFFu + ((u >> 16) & 1u)) >> 16;
    return (unsigned short)r;
}

// async global->LDS, 16B per lane. LDS dest must be wave-uniform base; HW writes base + lane*16.
__device__ __forceinline__ void load_lds16(const unsigned short* g, unsigned short* l) {
    __builtin_amdgcn_global_load_lds(
        (const __attribute__((address_space(1))) unsigned int*)g,
        (__attribute__((address_space(3))) unsigned int*)l,
        16, 0, 0);
}

// ---------------- prep: f32 -> bf16 conversion + per-row layer scalars ----------------
// grid (8192, 2): y-dim selects x (0) or y (1). 256 threads, 2 f32 each.
__global__ void prep_kernel(const float* __restrict__ xin, const float* __restrict__ yin,
                            unsigned short* __restrict__ xb, unsigned short* __restrict__ yb,
                            float* __restrict__ ax0, float* __restrict__ ax1,
                            float* __restrict__ ay0, float* __restrict__ ay1)
{
    const int row   = blockIdx.x;
    const int which = blockIdx.y;
    const float* src = (which ? yin : xin) + (size_t)row * D_K;
    unsigned short* dst = (which ? yb : xb) + (size_t)row * D_K;
    const int t = threadIdx.x;

    float2 v = ((const float2*)src)[t];
    ushort2 b; b.x = f2bf(v.x); b.y = f2bf(v.y);
    ((ushort2*)dst)[t] = b;

    float s = v.x * v.x + v.y * v.y;
    for (int o = 32; o > 0; o >>= 1) s += __shfl_down(s, o, 64);
    __shared__ float red[4];
    if ((t & 63) == 0) red[t >> 6] = s;
    __syncthreads();
    if (t == 0) {
        float tot = red[0] + red[1] + red[2] + red[3];
        float c0 = tot * (1.0f / D_K);
        float a0 = 1.0f + 2.0f * c0;
        // c1 = (2/pi) * asin(2 c0 / (1 + 2 c0))
        float c1 = 0.636619772367581343f * asinf(2.0f * c0 / (1.0f + 2.0f * c0));
        float a1 = 1.0f + 2.0f * c1;
        if (which) { ay0[row] = a0; ay1[row] = a1; }
        else       { ax0[row] = a0; ax1[row] = a1; }
    }
}

// one Erf layer + Dense: updates (nngp, ntk) given a = (1+2c) scalars for row/col
__device__ __forceinline__ void layer_step(float& nngp, float& ntk, float ax, float ay) {
    const float EPSF = 1e-7f;
    float prod  = ax * ay;
    float ratio = 2.0f * nngp * rsqrtf(prod);
    ratio = fminf(fmaxf(ratio, -1.0f + EPSF), 1.0f - EPSF);
    float nngp_new = 0.636619772367581343f * asinf(ratio);   // (2/pi) asin
    float d = prod - 4.0f * nngp * nngp;
    d = fmaxf(d, EPSF);
    float dot = 1.273239544735162686f * rsqrtf(d);           // (4/pi) rsqrt
    ntk  = ntk * dot + nngp_new;
    nngp = nngp_new;
}

// ---------------- main: bf16 MFMA GEMM (x @ y^T) + fused NTK epilogue ----------------
// 128x128 tile, BK=64, 4 waves (2x2 of 64x64), 16x16x32 bf16 MFMA.
__global__ void ntk_kernel(const unsigned short* __restrict__ xb,
                           const unsigned short* __restrict__ yb,
                           const float* __restrict__ ax0, const float* __restrict__ ax1,
                           const float* __restrict__ ay0, const float* __restrict__ ay1,
                           float* __restrict__ out)
{
    __shared__ unsigned short As[BM * BK];  // 16 KiB, row-major [128][64]
    __shared__ unsigned short Bs[BN * BK];  // 16 KiB, row-major [128][64] (y rows = C cols)

    const int tid  = threadIdx.x;
    const int lane = tid & 63;
    const int wid  = tid >> 6;
    const int wr   = wid >> 1;      // wave row (0..1)
    const int wc   = wid & 1;       // wave col (0..1)
    const int rowBase = blockIdx.y * BM;
    const int colBase = blockIdx.x * BN;
    const int l15 = lane & 15;
    const int lg  = lane >> 4;

    f32x4 acc[4][4];
    #pragma unroll
    for (int m = 0; m < 4; m++)
        #pragma unroll
        for (int n = 0; n < 4; n++)
            acc[m][n] = (f32x4){0.f, 0.f, 0.f, 0.f};

    for (int ks = 0; ks < D_K; ks += BK) {
        __syncthreads();  // previous compute done before overwriting LDS
        // stage A (16 KiB) + B (16 KiB): chunk = 16B; thread t of round r owns chunk r*256+t
        #pragma unroll
        for (int r = 0; r < 4; r++) {
            int base = r * 256 + wid * 64;     // wave-uniform chunk base
            int idx  = base + lane;
            int row  = idx >> 3;               // 8 chunks per 128B row
            int c    = idx & 7;
            const unsigned short* gA = xb + (size_t)(rowBase + row) * D_K + ks + c * 8;
            load_lds16(gA, &As[base * 8]);
            const unsigned short* gB = yb + (size_t)(colBase + row) * D_K + ks + c * 8;
            load_lds16(gB, &Bs[base * 8]);
        }
        __syncthreads();  // drains vmcnt -> staging visible

        // fragments: identical (lg, elem)->k mapping for A and B => layout-robust
        bf16x8 af[2][4], bfr[2][4];
        #pragma unroll
        for (int s = 0; s < 2; s++) {
            #pragma unroll
            for (int m = 0; m < 4; m++) {
                int rowA = wr * 64 + m * 16 + l15;
                af[s][m]  = *(const bf16x8*)&As[rowA * BK + s * 32 + lg * 8];
                int rowB = wc * 64 + m * 16 + l15;
                bfr[s][m] = *(const bf16x8*)&Bs[rowB * BK + s * 32 + lg * 8];
            }
        }
        #pragma unroll
        for (int s = 0; s < 2; s++)
            #pragma unroll
            for (int m = 0; m < 4; m++)
                #pragma unroll
                for (int n = 0; n < 4; n++)
                    acc[m][n] = __builtin_amdgcn_mfma_f32_16x16x32_bf16(
                        af[s][m], bfr[s][n], acc[m][n], 0, 0, 0);
    }

    // fused epilogue. C/D layout (m89-verified): col = lane&15, row = (lane>>4)*4 + reg
    float ay0v[4], ay1v[4];
    int   colv[4];
    #pragma unroll
    for (int n = 0; n < 4; n++) {
        int col = colBase + wc * 64 + n * 16 + l15;
        colv[n] = col;
        ay0v[n] = ay0[col];
        ay1v[n] = ay1[col];
    }
    #pragma unroll
    for (int m = 0; m < 4; m++) {
        int row0 = rowBase + wr * 64 + m * 16 + lg * 4;
        #pragma unroll
        for (int j = 0; j < 4; j++) {
            int row = row0 + j;
            float a0 = ax0[row], a1 = ax1[row];
            #pragma unroll
            for (int n = 0; n < 4; n++) {
                float nngp = acc[m][n][j] * (1.0f / D_K);
                float ntk = nngp;
                layer_step(nngp, ntk, a0, ay0v[n]);
                layer_step(nngp, ntk, a1, ay1v[n]);
                out[(size_t)row * NROW + colv[n]] = ntk;
            }
        }
    }
}

extern "C" void kernel_launch(void* const* d_in, const int* in_sizes, int n_in,
                              void* d_out, int out_size, void* d_ws, size_t ws_size,
                              hipStream_t stream)
{
    const float* x = (const float*)d_in[0];
    const float* y = (const float*)d_in[1];
    float* out = (float*)d_out;

    // workspace layout: xb (8 MiB) | yb (8 MiB) | ax0,ax1,ay0,ay1 (4*32 KiB)
    char* ws = (char*)d_ws;
    unsigned short* xb = (unsigned short*)ws;
    unsigned short* yb = (unsigned short*)(ws + (size_t)8 * 1024 * 1024);
    float* ax0 = (float*)(ws + (size_t)16 * 1024 * 1024);
    float* ax1 = ax0 + NROW;
    float* ay0 = ax1 + NROW;
    float* ay1 = ay0 + NROW;

    dim3 pgrid(NROW, 2);
    prep_kernel<<<pgrid, 256, 0, stream>>>(x, y, xb, yb, ax0, ax1, ay0, ay1);

    dim3 grid(NROW / BN, NROW / BM);
    ntk_kernel<<<grid, 256, 0, stream>>>(xb, yb, ax0, ax1, ay0, ay1, out);
}

// Round 2
// 136.231 us; speedup vs baseline: 1.3960x; 1.3960x over previous
//
#include <hip/hip_runtime.h>
#include <hip/hip_bf16.h>
#include <math.h>

#define D_K  512
#define NROW 8192
#define BM   128
#define BN   128
#define BK   64

typedef __attribute__((ext_vector_type(8))) short bf16x8;
typedef __attribute__((ext_vector_type(4))) float f32x4;

#if __has_builtin(__builtin_amdgcn_rsqf)
#define RSQ(x) __builtin_amdgcn_rsqf(x)
#else
#define RSQ(x) rsqrtf(x)
#endif

// f32 -> bf16 round-to-nearest-even
__device__ __forceinline__ unsigned short f2bf(float f) {
    unsigned int u = __float_as_uint(f);
    unsigned int r = (u + 0x7FFFu + ((u >> 16) & 1u)) >> 16;
    return (unsigned short)r;
}

// async global->LDS, 16B per lane (wave-uniform LDS base; HW writes base + lane*16)
__device__ __forceinline__ void load_lds16(const unsigned short* g, unsigned short* l) {
    __builtin_amdgcn_global_load_lds(
        (const __attribute__((address_space(1))) unsigned int*)g,
        (__attribute__((address_space(3))) unsigned int*)l,
        16, 0, 0);
}

// ---------------- prep: f32 -> bf16 + per-row epilogue scalars ----------------
// Stores px_l = 2/sqrt(1+2c_l) for x-rows, py_l = 1/sqrt(1+2c_l) for y-rows.
__global__ void prep_kernel(const float* __restrict__ xin, const float* __restrict__ yin,
                            unsigned short* __restrict__ xb, unsigned short* __restrict__ yb,
                            float* __restrict__ px0, float* __restrict__ px1,
                            float* __restrict__ py0, float* __restrict__ py1)
{
    const int row   = blockIdx.x;
    const int which = blockIdx.y;
    const float* src = (which ? yin : xin) + (size_t)row * D_K;
    unsigned short* dst = (which ? yb : xb) + (size_t)row * D_K;
    const int t = threadIdx.x;

    float2 v = ((const float2*)src)[t];
    ushort2 b; b.x = f2bf(v.x); b.y = f2bf(v.y);
    ((ushort2*)dst)[t] = b;

    float s = v.x * v.x + v.y * v.y;
    for (int o = 32; o > 0; o >>= 1) s += __shfl_down(s, o, 64);
    __shared__ float red[4];
    if ((t & 63) == 0) red[t >> 6] = s;
    __syncthreads();
    if (t == 0) {
        float tot = red[0] + red[1] + red[2] + red[3];
        float c0 = tot * (1.0f / D_K);
        float a0 = 1.0f + 2.0f * c0;
        float c1 = 0.636619772367581343f * asinf(2.0f * c0 / a0);
        float a1 = 1.0f + 2.0f * c1;
        if (which) {
            py0[row] = 1.0f / sqrtf(a0);
            py1[row] = 1.0f / sqrtf(a1);
        } else {
            px0[row] = 2.0f / sqrtf(a0);
            px1[row] = 2.0f / sqrtf(a1);
        }
    }
}

// one Erf layer + Dense, analytic, cheap:
//   s = px*py = 2*rsqrt(prod); ratio = nngp*s;
//   nngp' = (2/pi)*asin(ratio)   [odd Taylor to r^13, (2/pi) folded in]
//   dot   = (4/pi)*rsqrt(prod - 4 nngp^2) = (2/pi)*s*rsq(1 - ratio^2)
//   ntk   = ntk*dot + nngp'
__device__ __forceinline__ void layer_step(float& nngp, float& ntk, float s) {
    float ratio = nngp * s;
    ratio = fminf(fmaxf(ratio, -0.9999999f), 0.9999999f);
    float u = ratio * ratio;
    float p = fmaf(u, 0.011046346f, 0.014241648f);   // (2/pi)*{a13, a11}
    p = fmaf(u, p, 0.019340246f);                    // (2/pi)*a9
    p = fmaf(u, p, 0.028420525f);                    // (2/pi)*a7
    p = fmaf(u, p, 0.047746483f);                    // (2/pi)*a5
    p = fmaf(u, p, 0.106103295f);                    // (2/pi)*a3
    p = fmaf(u, p, 0.636619772f);                    // (2/pi)
    float nngp_new = ratio * p;
    float rv = RSQ(1.0f - u);
    float dot = 0.636619772f * (s * rv);
    ntk = fmaf(ntk, dot, nngp_new);
    nngp = nngp_new;
}

// ---------------- main: bf16 MFMA GEMM (x @ y^T) + fused NTK epilogue ----------------
// 128x128 tile, BK=64, 4 waves (2x2 of 64x64), 16x16x32 bf16 MFMA.
// LDS tiles use the T21 XOR swizzle: 16B slot (row, t) holds k-chunk t^(row&7);
// staged via pre-swizzled GLOBAL source (linear global_load_lds dest), read with
// the same XOR. Pure storage permutation -> MFMA k-pairing unchanged.
__global__ void ntk_kernel(const unsigned short* __restrict__ xb,
                           const unsigned short* __restrict__ yb,
                           const float* __restrict__ px0, const float* __restrict__ px1,
                           const float* __restrict__ py0, const float* __restrict__ py1,
                           float* __restrict__ out)
{
    __shared__ unsigned short As[BM * BK];  // 16 KiB
    __shared__ unsigned short Bs[BN * BK];  // 16 KiB

    const int tid  = threadIdx.x;
    const int lane = tid & 63;
    const int wid  = tid >> 6;
    const int wr   = wid >> 1;
    const int wc   = wid & 1;
    const int rowBase = blockIdx.y * BM;
    const int colBase = blockIdx.x * BN;
    const int l15 = lane & 15;
    const int lg  = lane >> 4;

    f32x4 acc[4][4];
    #pragma unroll
    for (int m = 0; m < 4; m++)
        #pragma unroll
        for (int n = 0; n < 4; n++)
            acc[m][n] = (f32x4){0.f, 0.f, 0.f, 0.f};

    for (int ks = 0; ks < D_K; ks += BK) {
        __syncthreads();
        // stage A + B, 16B chunks; chunk idx -> (row = idx>>3, slot t = idx&7)
        // slot t receives global k-chunk c = t ^ (row&7)  (inverse-swizzled source)
        #pragma unroll
        for (int r = 0; r < 4; r++) {
            int base = r * 256 + wid * 64;     // wave-uniform chunk base
            int idx  = base + lane;
            int row  = idx >> 3;
            int c    = (idx & 7) ^ (row & 7);
            const unsigned short* gA = xb + (size_t)(rowBase + row) * D_K + ks + c * 8;
            load_lds16(gA, &As[base * 8]);
            const unsigned short* gB = yb + (size_t)(colBase + row) * D_K + ks + c * 8;
            load_lds16(gB, &Bs[base * 8]);
        }
        __syncthreads();

        // fragment reads with matching XOR: logical scol = s*4+lg, slot = scol^(row&7)
        bf16x8 af[2][4], bfr[2][4];
        #pragma unroll
        for (int s = 0; s < 2; s++) {
            #pragma unroll
            for (int m = 0; m < 4; m++) {
                int rowA = wr * 64 + m * 16 + l15;
                int slA  = ((s * 4 + lg) ^ (rowA & 7)) * 8;
                af[s][m] = *(const bf16x8*)&As[rowA * BK + slA];
                int rowB = wc * 64 + m * 16 + l15;
                int slB  = ((s * 4 + lg) ^ (rowB & 7)) * 8;
                bfr[s][m] = *(const bf16x8*)&Bs[rowB * BK + slB];
            }
        }
        #pragma unroll
        for (int s = 0; s < 2; s++)
            #pragma unroll
            for (int m = 0; m < 4; m++)
                #pragma unroll
                for (int n = 0; n < 4; n++)
                    acc[m][n] = __builtin_amdgcn_mfma_f32_16x16x32_bf16(
                        af[s][m], bfr[s][n], acc[m][n], 0, 0, 0);
    }

    // fused epilogue. C/D layout: col = lane&15, row = (lane>>4)*4 + reg
    float py0v[4], py1v[4];
    int   colv[4];
    #pragma unroll
    for (int n = 0; n < 4; n++) {
        int col = colBase + wc * 64 + n * 16 + l15;
        colv[n] = col;
        py0v[n] = py0[col];
        py1v[n] = py1[col];
    }
    #pragma unroll
    for (int m = 0; m < 4; m++) {
        int row0 = rowBase + wr * 64 + m * 16 + lg * 4;
        #pragma unroll
        for (int j = 0; j < 4; j++) {
            int row = row0 + j;
            float a0 = px0[row], a1 = px1[row];
            #pragma unroll
            for (int n = 0; n < 4; n++) {
                float nngp = acc[m][n][j] * (1.0f / D_K);
                float ntk = nngp;
                layer_step(nngp, ntk, a0 * py0v[n]);
                layer_step(nngp, ntk, a1 * py1v[n]);
                out[(size_t)row * NROW + colv[n]] = ntk;
            }
        }
    }
}

extern "C" void kernel_launch(void* const* d_in, const int* in_sizes, int n_in,
                              void* d_out, int out_size, void* d_ws, size_t ws_size,
                              hipStream_t stream)
{
    const float* x = (const float*)d_in[0];
    const float* y = (const float*)d_in[1];
    float* out = (float*)d_out;

    char* ws = (char*)d_ws;
    unsigned short* xb = (unsigned short*)ws;
    unsigned short* yb = (unsigned short*)(ws + (size_t)8 * 1024 * 1024);
    float* px0 = (float*)(ws + (size_t)16 * 1024 * 1024);
    float* px1 = px0 + NROW;
    float* py0 = px1 + NROW;
    float* py1 = py0 + NROW;

    dim3 pgrid(NROW, 2);
    prep_kernel<<<pgrid, 256, 0, stream>>>(x, y, xb, yb, px0, px1, py0, py1);

    dim3 grid(NROW / BN, NROW / BM);
    ntk_kernel<<<grid, 256, 0, stream>>>(xb, yb, px0, px1, py0, py1, out);
}